// Round 2
// baseline (749.624 us; speedup 1.0000x reference)
//
#include <hip/hip_runtime.h>
#include <hip/hip_bf16.h>

// RGCN layer, MI355X — round 13 (r12 resubmit; container infra failure, no
// counters returned; audit found no hang/fault path).
// r11 theory: conv (84us, 40% HBM, 10% MFMA) is bound by the 164MB bf16
// per-edge intermediate round-trip (write in conv, read in reduce).
// STRUCTURE: kill t_buf. Edges bucketed by key=(dst>>6)*65+etype
// (20345 buckets, mean 31.5 edges). Fused conv blocks own
// (64-dst group, 64-col half, rel half): loop rels, stage W-half (16KB) +
// gathered A rows in LDS, MFMA, accumulate f32 in LDS hloc[64][65] via
// ds-atomics, write h-partial once (natural cols). Reduce kernel becomes a
// 40MB combine; bn becomes pure elementwise. Everything natural-order now.

#define N_NODES 20000
#define E_EDGES 640000
#define R_REL   65
#define NGRP    313                 // ceil(20000/64)
#define NKEY    (NGRP * R_REL)      // 20345
#define NB_CONV (NGRP * 4)          // (g, colhalf, relhalf) = 1252
#define NB_RES  (NGRP * 2)          // (rowgrp, colhalf)     = 626

typedef __attribute__((ext_vector_type(8))) short bf16x8;
typedef __attribute__((ext_vector_type(4))) float f32x4;
typedef __attribute__((ext_vector_type(2))) unsigned int u32x2;

__device__ __forceinline__ unsigned short f2bf(float x) {
    union { float f; unsigned int u; } c; c.f = x;
    unsigned int b = c.u + 0x7fffu + ((c.u >> 16) & 1u);   // RTNE
    return (unsigned short)(b >> 16);
}
__device__ __forceinline__ void async16(const void* g, void* l) {
    __builtin_amdgcn_global_load_lds(
        (const __attribute__((address_space(1))) unsigned int*)g,
        (__attribute__((address_space(3))) unsigned int*)l, 16, 0, 0);
}

// ---------------- K1: basis GEMM || key histogram || f32->bf16 cvt ---------
__global__ void k_prep1(const float* __restrict__ comp, const float* __restrict__ basis,
                        float* __restrict__ W32, const int* __restrict__ et,
                        const int* __restrict__ dstA, int* __restrict__ gh3,
                        const float* __restrict__ node_feats,
                        unsigned short* __restrict__ node_bf) {
    __shared__ float lc[16 * 65];
    int b = blockIdx.x, t = threadIdx.x;
    if (b < 320) {                                  // basis GEMM: W32 = comp @ basis
        int r0 = (b >> 6) * 16;
        int col = (b & 63) * 256 + t;
        for (int j = t; j < 16 * 65; j += 256) {
            int rr = r0 + j / 65;
            lc[j] = (rr < R_REL) ? comp[rr * 65 + (j % 65)] : 0.f;
        }
        __syncthreads();
        float acc[16];
#pragma unroll
        for (int j = 0; j < 16; ++j) acc[j] = 0.f;
        for (int k = 0; k < 65; ++k) {
            float v = basis[k * 16384 + col];
#pragma unroll
            for (int j = 0; j < 16; ++j) acc[j] += lc[j * 65 + k] * v;
        }
#pragma unroll
        for (int j = 0; j < 16; ++j) {
            int rr = r0 + j;
            if (rr < R_REL) W32[rr * 16384 + col] = acc[j];
        }
    } else if (b < 832) {                           // per-(dstgrp,rel) histogram
        for (int i = (b - 320) * 256 + t; i < E_EDGES; i += 512 * 256)
            atomicAdd(&gh3[(dstA[i] >> 6) * 65 + et[i]], 1);
    } else {                                        // cvt fp32 -> bf16 (x4)
        int i = (b - 832) * 256 + t;
        if (i < N_NODES * 32) {
            float4 v = reinterpret_cast<const float4*>(node_feats)[i];
            __hip_bfloat162 b0 = __float22bfloat162_rn(make_float2(v.x, v.y));
            __hip_bfloat162 b1 = __float22bfloat162_rn(make_float2(v.z, v.w));
            u32x2 pk;
            pk.x = *reinterpret_cast<unsigned int*>(&b0);
            pk.y = *reinterpret_cast<unsigned int*>(&b1);
            reinterpret_cast<u32x2*>(node_bf)[i] = pk;
        }
    }
}

// ---------------- K2: key scan (self prefix) || W transposes ---------------
__global__ void k_prep2(const int* __restrict__ gh3, int* __restrict__ segK,
                        int* __restrict__ cnt3, const float* __restrict__ W32,
                        unsigned short* __restrict__ Wt, const float* __restrict__ Wresf,
                        unsigned short* __restrict__ Wrest) {
    int b = blockIdx.x, t = threadIdx.x;
    if (b < 80) {                                   // scan 20345 keys
        __shared__ int red[256];
        __shared__ int pref;
        int acc = 0;
        for (int i = t; i < b * 256; i += 256) acc += gh3[i];
        red[t] = acc;
        __syncthreads();
        for (int off = 128; off > 0; off >>= 1) {
            if (t < off) red[t] += red[t + off];
            __syncthreads();
        }
        if (t == 0) pref = red[0];
        __syncthreads();
        int i = b * 256 + t;
        int v = (i < NKEY) ? gh3[i] : 0;
        red[t] = v;
        __syncthreads();
        for (int off = 1; off < 256; off <<= 1) {
            int x = (t >= off) ? red[t - off] : 0;
            __syncthreads();
            red[t] += x;
            __syncthreads();
        }
        int excl = red[t] - v + pref;
        if (i < NKEY) {
            segK[i] = excl;
            cnt3[i] = excl;
            if (i == NKEY - 1) segK[NKEY] = excl + v;
        }
    } else {                                        // transposes (264 blocks)
        __shared__ float tile[64][65];
        int bb = b - 80;
        const float* s; unsigned short* d; int sub;
        if (bb < R_REL * 4) { s = W32 + (size_t)(bb >> 2) * 16384; d = Wt + (size_t)(bb >> 2) * 16384; sub = bb & 3; }
        else { s = Wresf; d = Wrest; sub = bb - R_REL * 4; }
        int ot = (sub >> 1) & 1, itl = sub & 1;
        int tx = t & 63, ty = t >> 6;
        for (int it = 0; it < 16; ++it) {
            int i = ty + it * 4;
            tile[i][tx] = s[(itl * 64 + i) * 128 + ot * 64 + tx];
        }
        __syncthreads();
        for (int it = 0; it < 16; ++it) {
            int o = ty + it * 4;
            d[(ot * 64 + o) * 128 + itl * 64 + tx] = f2bf(tile[tx][o]);
        }
    }
}

// ---------------- K3: bucket scatter (one edge per thread) -----------------
__global__ void k_scatter(const int* __restrict__ et, const int* __restrict__ srcA,
                          const int* __restrict__ dstA, const float* __restrict__ norm,
                          int* __restrict__ cnt3, int* __restrict__ ssd,
                          float* __restrict__ normd) {
    int i = blockIdx.x * 256 + threadIdx.x;
    if (i >= E_EDGES) return;
    int d = dstA[i];
    int key = (d >> 6) * 65 + et[i];
    int p = atomicAdd(&cnt3[key], 1);
    ssd[p] = srcA[i] | ((d & 63) << 15);            // src 15b | slot 6b
    normd[p] = norm[i];
}

// ---------------- K4: fused conv (LDS-accumulated) + resid GEMM ------------
__global__ __launch_bounds__(256, 3) void k_fused(
    const int* __restrict__ segK, const int* __restrict__ ssd,
    const float* __restrict__ normd, const unsigned short* __restrict__ node_bf,
    const unsigned short* __restrict__ Wt, const unsigned short* __restrict__ Wrest,
    const float* __restrict__ b_res, float* __restrict__ hp0,
    float* __restrict__ hp1, float* __restrict__ resid) {
    __shared__ unsigned short Alds[64 * 128];       // 16 KB
    __shared__ unsigned short Blds[64 * 128];       // 16 KB (W col-half)
    __shared__ float hloc[64][65];                  // 16.6 KB f32 accumulator
    __shared__ float snorm[64];
    __shared__ int sslot[64];
    __shared__ int sseg[34];
    int t = threadIdx.x;
    int w = t >> 6, lane = t & 63;
    int lrow = lane & 15, quad = lane >> 4;
    int wc = (w >> 1) * 32;                         // col offset in 64-col half
    int rbase = (w & 1) * 16;                       // row offset in 32-row pass

    if (blockIdx.x >= NB_CONV) {
        // ---- residual tile: relu(x @ W_res[:,ch*64:+64] + b) -> resid
        int rb = blockIdx.x - NB_CONV;
        int row0 = (rb >> 1) * 64, ch = rb & 1;
        int nrows = min(64, N_NODES - row0);
#pragma unroll
        for (int it = 0; it < 4; ++it) {
            int j = t + 256 * it;
            int o = j >> 4, c = j & 15, cs = c ^ (o & 15);
            async16(Wrest + (size_t)(ch * 64 + o) * 128 + cs * 8, &Blds[o * 128 + c * 8]);
        }
#pragma unroll
        for (int it = 0; it < 4; ++it) {
            int j = t + 256 * it;
            int p = j >> 4, c = j & 15, cs = c ^ (p & 15);
            if (p < nrows)
                async16(node_bf + (size_t)(row0 + p) * 128 + cs * 8, &Alds[p * 128 + c * 8]);
        }
        float bb0 = b_res[ch * 64 + wc + lrow];
        float bb1 = b_res[ch * 64 + wc + 16 + lrow];
        __syncthreads();
#pragma unroll
        for (int pass = 0; pass < 2; ++pass) {
            int r0 = pass * 32 + rbase;
            if (r0 >= nrows) break;
            f32x4 acc0 = {0.f, 0.f, 0.f, 0.f}, acc1 = {0.f, 0.f, 0.f, 0.f};
#pragma unroll
            for (int ks = 0; ks < 4; ++ks) {
                int cs = (ks * 4 + quad) ^ lrow;
                bf16x8 a  = *reinterpret_cast<const bf16x8*>(&Alds[(r0 + lrow) * 128 + cs * 8]);
                bf16x8 b0 = *reinterpret_cast<const bf16x8*>(&Blds[(wc + lrow) * 128 + cs * 8]);
                bf16x8 b1 = *reinterpret_cast<const bf16x8*>(&Blds[(wc + 16 + lrow) * 128 + cs * 8]);
                acc0 = __builtin_amdgcn_mfma_f32_16x16x32_bf16(a, b0, acc0, 0, 0, 0);
                acc1 = __builtin_amdgcn_mfma_f32_16x16x32_bf16(a, b1, acc1, 0, 0, 0);
            }
#pragma unroll
            for (int reg = 0; reg < 4; ++reg) {
                int row = r0 + quad * 4 + reg;
                if (row < nrows) {
                    float* rp = resid + (size_t)(row0 + row) * 128 + ch * 64;
                    rp[wc + lrow]      = fmaxf(acc0[reg] + bb0, 0.f);
                    rp[wc + 16 + lrow] = fmaxf(acc1[reg] + bb1, 0.f);
                }
            }
        }
        return;
    }

    // ---- conv block: (group g, col-half ch, rel-half rh)
    int g = blockIdx.x >> 2;
    int ch = (blockIdx.x >> 1) & 1, rh = blockIdx.x & 1;
    int nrel = rh ? 32 : 33;
    int key0 = g * 65 + rh * 33;
    if (t <= nrel) sseg[t] = segK[key0 + t];
    for (int i = t; i < 64 * 65; i += 256) (&hloc[0][0])[i] = 0.f;
    __syncthreads();

    for (int rr = 0; rr < nrel; ++rr) {
        int base = sseg[rr], cnt = sseg[rr + 1] - base;
        if (cnt == 0) continue;
        int r = rh * 33 + rr;
        for (int t0 = 0; t0 < cnt; t0 += 64) {
            int rows = min(64, cnt - t0);
            __syncthreads();                        // Alds/Blds reuse guard
            if (t0 == 0) {                          // stage W_r col-half
#pragma unroll
                for (int it = 0; it < 4; ++it) {
                    int j = t + 256 * it;
                    int o = j >> 4, c = j & 15, cs = c ^ (o & 15);
                    async16(Wt + (size_t)r * 16384 + (size_t)(ch * 64 + o) * 128 + cs * 8,
                            &Blds[o * 128 + c * 8]);
                }
            }
#pragma unroll
            for (int it = 0; it < 4; ++it) {        // gather A rows
                int j = t + 256 * it;
                int p = j >> 4, c = j & 15, cs = c ^ (p & 15);
                if (p < rows) {
                    int src = ssd[base + t0 + p] & 0x7fff;
                    async16(node_bf + (size_t)src * 128 + cs * 8, &Alds[p * 128 + c * 8]);
                }
            }
            if (t < rows) {
                int pk = ssd[base + t0 + t];
                sslot[t] = pk >> 15;
                snorm[t] = normd[base + t0 + t];
            }
            __syncthreads();
#pragma unroll
            for (int pass = 0; pass < 2; ++pass) {
                int r0 = pass * 32 + rbase;
                if (r0 >= rows) break;
                f32x4 acc0 = {0.f, 0.f, 0.f, 0.f}, acc1 = {0.f, 0.f, 0.f, 0.f};
#pragma unroll
                for (int ks = 0; ks < 4; ++ks) {
                    int cs = (ks * 4 + quad) ^ lrow;
                    bf16x8 a  = *reinterpret_cast<const bf16x8*>(&Alds[(r0 + lrow) * 128 + cs * 8]);
                    bf16x8 b0 = *reinterpret_cast<const bf16x8*>(&Blds[(wc + lrow) * 128 + cs * 8]);
                    bf16x8 b1 = *reinterpret_cast<const bf16x8*>(&Blds[(wc + 16 + lrow) * 128 + cs * 8]);
                    acc0 = __builtin_amdgcn_mfma_f32_16x16x32_bf16(a, b0, acc0, 0, 0, 0);
                    acc1 = __builtin_amdgcn_mfma_f32_16x16x32_bf16(a, b1, acc1, 0, 0, 0);
                }
#pragma unroll
                for (int reg = 0; reg < 4; ++reg) {
                    int row = r0 + quad * 4 + reg;
                    if (row < rows) {               // garbage rows never touch hloc
                        float nm = snorm[row];
                        int sl = sslot[row];
                        atomicAdd(&hloc[sl][wc + lrow],      acc0[reg] * nm);
                        atomicAdd(&hloc[sl][wc + 16 + lrow], acc1[reg] * nm);
                    }
                }
            }
        }
    }
    __syncthreads();
    float* hp = rh ? hp1 : hp0;
#pragma unroll
    for (int it = 0; it < 16; ++it) {
        int idx = t + 256 * it;
        int sl = idx >> 6, c = idx & 63;
        int node = g * 64 + sl;
        if (node < N_NODES) hp[(size_t)node * 128 + ch * 64 + c] = hloc[sl][c];
    }
}

// ---------------- K5: combine partials + relu + resid + BN stats -----------
__global__ __launch_bounds__(256) void k_combine(
    const float* __restrict__ hp0, const float* __restrict__ hp1,
    const float* __restrict__ resid, const float* __restrict__ h_bias,
    float* __restrict__ h, float* __restrict__ colsum, float* __restrict__ colsumsq) {
    __shared__ float cs1[128], cs2[128], sbias[128];
    int t = threadIdx.x;
    if (t < 128) { cs1[t] = 0.f; cs2[t] = 0.f; sbias[t] = h_bias[t]; }
    __syncthreads();
    int c4 = (t & 31) * 4;
#pragma unroll
    for (int pass = 0; pass < 2; ++pass) {
        int row = blockIdx.x * 16 + pass * 8 + (t >> 5);
        size_t off = (size_t)row * 128 + c4;
        f32x4 va = *reinterpret_cast<const f32x4*>(hp0 + off);
        f32x4 vb = *reinterpret_cast<const f32x4*>(hp1 + off);
        f32x4 vr = *reinterpret_cast<const f32x4*>(resid + off);
        f32x4 v;
#pragma unroll
        for (int k = 0; k < 4; ++k)
            v[k] = fmaxf(va[k] + vb[k] + sbias[c4 + k], 0.f) + vr[k];
        *reinterpret_cast<f32x4*>(h + off) = v;
#pragma unroll
        for (int k = 0; k < 4; ++k) {
            atomicAdd(&cs1[c4 + k], v[k]);
            atomicAdd(&cs2[c4 + k], v[k] * v[k]);
        }
    }
    __syncthreads();
    if (t < 128) {
        atomicAdd(&colsum[t], cs1[t]);
        atomicAdd(&colsumsq[t], cs2[t]);
    }
}

// ---------------- K6: BN apply (natural cols, pure elementwise) ------------
__global__ void k_bn(float* __restrict__ h, const float* __restrict__ colsum,
                     const float* __restrict__ colsumsq, const float* __restrict__ gamma,
                     const float* __restrict__ beta) {
    __shared__ float sc[128], sh2[128];
    int t = threadIdx.x;
    if (t < 128) {
        float m = colsum[t] * (1.f / N_NODES);
        float var = colsumsq[t] * (1.f / N_NODES) - m * m;
        float s = gamma[t] * rsqrtf(var + 1e-5f);
        sc[t] = s;
        sh2[t] = beta[t] - m * s;
    }
    __syncthreads();
    int i = blockIdx.x * 256 + t;                   // one f32x4 per thread
    if (i < N_NODES * 32) {
        int row = i >> 5, c4 = (i & 31) * 4;
        f32x4 v = *reinterpret_cast<f32x4*>(h + (size_t)row * 128 + c4);
#pragma unroll
        for (int k = 0; k < 4; ++k) v[k] = v[k] * sc[c4 + k] + sh2[c4 + k];
        *reinterpret_cast<f32x4*>(h + (size_t)row * 128 + c4) = v;
    }
}

extern "C" void kernel_launch(void* const* d_in, const int* in_sizes, int n_in,
                              void* d_out, int out_size, void* d_ws, size_t ws_size,
                              hipStream_t stream) {
    (void)in_sizes; (void)n_in; (void)out_size; (void)ws_size;
    const float* node_feats = (const float*)d_in[0];
    const int* src    = (const int*)d_in[1];
    const int* dst    = (const int*)d_in[2];
    const int* etype  = (const int*)d_in[3];
    const float* norm = (const float*)d_in[4];
    const float* basis = (const float*)d_in[5];
    const float* comp  = (const float*)d_in[6];
    const float* h_bias = (const float*)d_in[7];
    const float* W_res  = (const float*)d_in[8];
    const float* b_res  = (const float*)d_in[9];
    const float* gamma  = (const float*)d_in[10];
    const float* beta   = (const float*)d_in[11];

    char* ws = (char*)d_ws;
    float* colsum   = (float*)(ws + 0);            // 512
    float* colsumsq = (float*)(ws + 512);          // 512
    int* gh3        = (int*)(ws + 1024);           // 81380 -> 82404
    int* segK       = (int*)(ws + 82432);          // 81384 -> 163816
    int* cnt3       = (int*)(ws + 163840);         // 81380 -> 245220
    int* ssd        = (int*)(ws + 245248);         // 2560000 -> 2805248
    float* normd    = (float*)(ws + 2805248);      // 2560000 -> 5365248
    unsigned short* Wt      = (unsigned short*)(ws + 5365248);   // 2129920 -> 7495168
    unsigned short* Wrest   = (unsigned short*)(ws + 7495168);   // 32768   -> 7527936
    unsigned short* node_bf = (unsigned short*)(ws + 7527936);   // 5120000 -> 12647936
    float* resid    = (float*)(ws + 12647936);     // 10240000 -> 22887936
    float* hp0      = (float*)(ws + 22887936);     // 10240000 -> 33127936
    float* hp1      = (float*)(ws + 33127936);     // 10240000 -> 43367936
    float* W32      = (float*)(ws + 43367936);     // 4259840  -> 47627776
    float* h = (float*)d_out;

    hipMemsetAsync(ws, 0, 82432, stream);          // colsum, colsumsq, gh3
    k_prep1<<<3332, 256, 0, stream>>>(comp, basis, W32, etype, dst, gh3,
                                      node_feats, node_bf);
    k_prep2<<<344, 256, 0, stream>>>(gh3, segK, cnt3, W32, Wt, W_res, Wrest);
    k_scatter<<<2500, 256, 0, stream>>>(etype, src, dst, norm, cnt3, ssd, normd);
    k_fused<<<NB_CONV + NB_RES, 256, 0, stream>>>(segK, ssd, normd, node_bf,
                                                  Wt, Wrest, b_res, hp0, hp1, resid);
    k_combine<<<1250, 256, 0, stream>>>(hp0, hp1, resid, h_bias, h, colsum, colsumsq);
    k_bn<<<2500, 256, 0, stream>>>(h, colsum, colsumsq, gamma, beta);
}